// Round 6
// baseline (475.635 us; speedup 1.0000x reference)
//
#include <hip/hip_runtime.h>
#include <math.h>

#define PI2 6.28318530717958647692f

// Problem constants: B=32, CI=CO=64, H=W=128, M1=M2=32.
// Intermediates:
//   Yimg [bi=2048][p=4][ky=32][h=128] ushort (bf16 planes, swizzled)  (buf1, 64 MB)
//   Xf   [kxi=64][bi=2048][ky=32] float2   (buf2)  <- mode-gather-friendly layout
//   T    [mode=kxi*32+ky][bo=2048] float2  (buf1)  <- mix writes coalesced
// out [b=32][o=64][h=128][w'=65] fp32  (written directly by fused k_inv)
// Swizzle (bf16 LDS images, granule = 8 ushorts): idx = row*S + (oct ^ f(row))*8 + j

typedef short bf16x8 __attribute__((ext_vector_type(8)));
typedef float f32x4 __attribute__((ext_vector_type(4)));

static __device__ __forceinline__ ushort f2bf(float f) {
    uint u = __float_as_uint(f);
    u += 0x7FFFu + ((u >> 16) & 1u);  // round-to-nearest-even
    return (ushort)(u >> 16);
}
static __device__ __forceinline__ float bf2f(ushort h) {
    return __uint_as_float(((uint)h) << 16);
}

// ---------------- Twiddle init: E1, E2, EC, EW images ------------------------
__global__ void k_einit(ushort* __restrict__ e1, ushort* __restrict__ e2,
                        ushort* __restrict__ ec, ushort* __restrict__ ew) {
    int id = blockIdx.x * 256 + threadIdx.x;
    if (id < 8192) {
        int w = id & 127, col = id >> 7;
        int ky = col & 31, csel = col >> 5;
        int m = (ky * w) & 127;
        float sv, cv;
        sincosf((float)m * (PI2 / 128.0f), &sv, &cv);
        float val = csel ? -sv : cv;
        ushort hi = f2bf(val);
        int ui = col * 128 + (w ^ ((col & 7) << 3));
        e1[ui] = hi;
        e1[8192 + ui] = f2bf(val - bf2f(hi));
    } else if (id < 16384) {
        int id2 = id - 8192;
        int h = id2 & 127, kxi = id2 >> 7;
        int kx = (kxi < 32) ? kxi : (kxi + 64);
        int m = (kx * h) & 127;
        float sv, cv;
        sincosf((float)m * (PI2 / 128.0f), &sv, &cv);
        float er = cv, ei = -sv;
        int ui = kxi * 128 + (h ^ ((kxi & 7) << 3));
        ushort eh = f2bf(er);
        e2[ui] = eh;
        e2[8192 + ui] = f2bf(er - bf2f(eh));
        ushort ih = f2bf(ei);
        e2[16384 + ui] = ih;
        e2[24576 + ui] = f2bf(ei - bf2f(ih));
    } else if (id < 32768) {
        int id2 = id - 16384;
        int j = id2 & 7, ln = (id2 >> 3) & 15, kq = (id2 >> 7) & 3,
            kk = (id2 >> 9) & 3, mt = id2 >> 11;
        int h = mt * 16 + ln;
        int k = kk * 32 + kq * 8 + j;
        int kc = (k < 64) ? k : (k - 64);
        int kx = (kc < 32) ? kc : (kc + 64);
        int m = (kx * h) & 127;
        float sv, cv;
        sincosf((float)m * (PI2 / 128.0f), &sv, &cv);
        float val = ((k < 64) ? cv : sv) * (1.0f / 8320.0f);
        ushort hi = f2bf(val);
        ec[id2] = hi;
        ec[16384 + id2] = f2bf(val - bf2f(hi));
    } else if (id < 40448) {
        int id3 = id - 32768;
        int off = id3 % 2560, pe = id3 / 2560;   // pe 0=Cw 1=Sw 2=-Sw
        int j = off & 7, ln = (off >> 3) & 15, kq = (off >> 7) & 3, nt1 = off >> 9;
        int ky = kq * 8 + j, w = nt1 * 16 + ln;
        float val = 0.0f;
        if (w < 65) {
            int m = (w * ky) % 65;
            float sv, cv;
            sincosf((float)m * (PI2 / 65.0f), &sv, &cv);
            val = (pe == 0) ? cv : ((pe == 1) ? sv : -sv);
        }
        ushort hi = f2bf(val);
        ew[pe * 5120 + off] = hi;
        ew[pe * 5120 + 2560 + off] = f2bf(val - bf2f(hi));
    }
}

// ---------------- Stage F1 (MFMA): x -> Yimg (row DFT over W, 32 modes) ------
__global__ __launch_bounds__(256) void k_f1(const float* __restrict__ x,
                                            const ushort* __restrict__ eimg,
                                            ushort* __restrict__ yimg) {
    __shared__ ushort lds[32768];  // 64 KiB
    const int bi = blockIdx.x;
    const int hbase = blockIdx.y * 64;
    const int t = threadIdx.x;

    {
        const uint4* esrc = (const uint4*)eimg;
        uint4* edst = (uint4*)lds;
        for (int i = t; i < 2048; i += 256) edst[i] = esrc[i];
    }

    const float* xp = x + (size_t)bi * 16384 + (size_t)hbase * 128;
    for (int i = 0; i < 4; i++) {
        int idx = i * 2048 + t * 8;
        int row = idx >> 7, w0 = idx & 127;
        float4 v0 = *(const float4*)&xp[idx];
        float4 v1 = *(const float4*)&xp[idx + 4];
        float vv[8] = {v0.x, v0.y, v0.z, v0.w, v1.x, v1.y, v1.z, v1.w};
        ushort h[8], l[8];
#pragma unroll
        for (int j = 0; j < 8; j++) {
            h[j] = f2bf(vv[j]);
            l[j] = f2bf(vv[j] - bf2f(h[j]));
        }
        uint4 hp, lp;
        hp.x = (uint)h[0] | ((uint)h[1] << 16);
        hp.y = (uint)h[2] | ((uint)h[3] << 16);
        hp.z = (uint)h[4] | ((uint)h[5] << 16);
        hp.w = (uint)h[6] | ((uint)h[7] << 16);
        lp.x = (uint)l[0] | ((uint)l[1] << 16);
        lp.y = (uint)l[2] | ((uint)l[3] << 16);
        lp.z = (uint)l[4] | ((uint)l[5] << 16);
        lp.w = (uint)l[6] | ((uint)l[7] << 16);
        int ui = row * 128 + (w0 ^ ((row & 7) << 3));
        *(uint4*)&lds[16384 + ui] = hp;
        *(uint4*)&lds[24576 + ui] = lp;
    }
    __syncthreads();

    const int lane = t & 63, wid = t >> 6;
    const int ln = lane & 15, kq = lane >> 4;
    f32x4 acc[4] = {};
#pragma unroll
    for (int kk = 0; kk < 4; kk++) {
        int k0 = kk * 32 + kq * 8;
        int arow = wid * 16 + ln;
        int aui = arow * 128 + (k0 ^ ((arow & 7) << 3));
        bf16x8 ah = *(bf16x8*)&lds[16384 + aui];
        bf16x8 al = *(bf16x8*)&lds[24576 + aui];
#pragma unroll
        for (int nt = 0; nt < 4; nt++) {
            int col = nt * 16 + ln;
            int bui = col * 128 + (k0 ^ ((col & 7) << 3));
            bf16x8 bh = *(bf16x8*)&lds[bui];
            bf16x8 bl = *(bf16x8*)&lds[8192 + bui];
            acc[nt] = __builtin_amdgcn_mfma_f32_16x16x32_bf16(ah, bh, acc[nt], 0, 0, 0);
            acc[nt] = __builtin_amdgcn_mfma_f32_16x16x32_bf16(ah, bl, acc[nt], 0, 0, 0);
            acc[nt] = __builtin_amdgcn_mfma_f32_16x16x32_bf16(al, bh, acc[nt], 0, 0, 0);
        }
    }

    ushort* yp = yimg + (size_t)bi * 16384;
    const int h0 = hbase + wid * 16 + kq * 4;
#pragma unroll
    for (int nt = 0; nt < 4; nt++) {
        int col = nt * 16 + ln;
        int ky = col & 31, c = col >> 5;
        ushort4 h4, l4;
        float v0 = acc[nt][0], v1 = acc[nt][1], v2 = acc[nt][2], v3 = acc[nt][3];
        h4.x = f2bf(v0); l4.x = f2bf(v0 - bf2f(h4.x));
        h4.y = f2bf(v1); l4.y = f2bf(v1 - bf2f(h4.y));
        h4.z = f2bf(v2); l4.z = f2bf(v2 - bf2f(h4.z));
        h4.w = f2bf(v3); l4.w = f2bf(v3 - bf2f(h4.w));
        int hs = h0 ^ ((ky & 7) << 3);
        *(ushort4*)&yp[(c * 2) * 4096 + ky * 128 + hs] = h4;
        *(ushort4*)&yp[(c * 2 + 1) * 4096 + ky * 128 + hs] = l4;
    }
}

// ---------------- Stage F2 (MFMA): Yimg -> Xf (col DFT over H, 64 modes) -----
// Output layout: Xf[kxi][bi][ky] (mode-gather-friendly for k_mix).
__global__ __launch_bounds__(512) void k_f2(const ushort* __restrict__ yimg,
                                            const ushort* __restrict__ e2img,
                                            float2* __restrict__ xf) {
    __shared__ ushort lds[32768];  // 64 KiB
    const int t = threadIdx.x;
    const int bi0 = blockIdx.x * 8;

    uint4 R[4];
    {
        const uint4* ys = (const uint4*)(yimg + (size_t)bi0 * 16384);
#pragma unroll
        for (int c = 0; c < 4; c++) R[c] = ys[c * 512 + t];
    }
    {
        const uint4* es = (const uint4*)e2img;
        uint4* ed = (uint4*)lds;
        for (int i = t; i < 4096; i += 512) ed[i] = es[i];
    }
    __syncthreads();
    const int lane = t & 63, wid = t >> 6;
    const int ln = lane & 15, kq = lane >> 4;
    const int mt = wid >> 1, nt = wid & 1;
    const int arow = mt * 16 + ln;
    const int bcol = nt * 16 + ln;
    bf16x8 Erh[4], Erl[4], Eih[4], Eil[4];
#pragma unroll
    for (int kk = 0; kk < 4; kk++) {
        int k0 = kk * 32 + kq * 8;
        int ao = arow * 128 + (k0 ^ ((arow & 7) << 3));
        Erh[kk] = *(const bf16x8*)&lds[ao];
        Erl[kk] = *(const bf16x8*)&lds[8192 + ao];
        Eih[kk] = *(const bf16x8*)&lds[16384 + ao];
        Eil[kk] = *(const bf16x8*)&lds[24576 + ao];
    }
    __syncthreads();
    {
        uint4* yd = (uint4*)lds;
#pragma unroll
        for (int c = 0; c < 4; c++) yd[c * 512 + t] = R[c];
    }
    __syncthreads();

    int cur = 0;
    for (int j = 0; j < 8; j++) {
        const int bi = bi0 + j;
        if (j < 7) {
            const uint4* ys = (const uint4*)(yimg + (size_t)(bi + 1) * 16384);
#pragma unroll
            for (int c = 0; c < 4; c++) R[c] = ys[c * 512 + t];
        }
        const ushort* yb = &lds[cur * 16384];
        f32x4 P1 = {}, P2 = {}, P3 = {}, P4 = {};
#pragma unroll
        for (int kk = 0; kk < 4; kk++) {
            int k0 = kk * 32 + kq * 8;
            int bo = bcol * 128 + (k0 ^ ((bcol & 7) << 3));
            bf16x8 Yrh = *(const bf16x8*)&yb[bo];
            bf16x8 Yrl = *(const bf16x8*)&yb[4096 + bo];
            bf16x8 Yih = *(const bf16x8*)&yb[8192 + bo];
            bf16x8 Yil = *(const bf16x8*)&yb[12288 + bo];
            P1 = __builtin_amdgcn_mfma_f32_16x16x32_bf16(Erh[kk], Yrh, P1, 0, 0, 0);
            P1 = __builtin_amdgcn_mfma_f32_16x16x32_bf16(Erh[kk], Yrl, P1, 0, 0, 0);
            P1 = __builtin_amdgcn_mfma_f32_16x16x32_bf16(Erl[kk], Yrh, P1, 0, 0, 0);
            P2 = __builtin_amdgcn_mfma_f32_16x16x32_bf16(Eih[kk], Yih, P2, 0, 0, 0);
            P2 = __builtin_amdgcn_mfma_f32_16x16x32_bf16(Eih[kk], Yil, P2, 0, 0, 0);
            P2 = __builtin_amdgcn_mfma_f32_16x16x32_bf16(Eil[kk], Yih, P2, 0, 0, 0);
            P3 = __builtin_amdgcn_mfma_f32_16x16x32_bf16(Erh[kk], Yih, P3, 0, 0, 0);
            P3 = __builtin_amdgcn_mfma_f32_16x16x32_bf16(Erh[kk], Yil, P3, 0, 0, 0);
            P3 = __builtin_amdgcn_mfma_f32_16x16x32_bf16(Erl[kk], Yih, P3, 0, 0, 0);
            P4 = __builtin_amdgcn_mfma_f32_16x16x32_bf16(Eih[kk], Yrh, P4, 0, 0, 0);
            P4 = __builtin_amdgcn_mfma_f32_16x16x32_bf16(Eih[kk], Yrl, P4, 0, 0, 0);
            P4 = __builtin_amdgcn_mfma_f32_16x16x32_bf16(Eil[kk], Yrh, P4, 0, 0, 0);
        }
        // Store to Xf[kxi][bi][ky]: kxi = mt*16+kq*4+r, ky = bcol.
        float2* xp = xf + (size_t)(mt * 16 + kq * 4) * 65536 + (size_t)bi * 32 + bcol;
#pragma unroll
        for (int r = 0; r < 4; r++)
            xp[(size_t)r * 65536] = make_float2(P1[r] - P2[r], P3[r] + P4[r]);
        if (j < 7) {
            uint4* yd = (uint4*)&lds[(cur ^ 1) * 16384];
#pragma unroll
            for (int c = 0; c < 4; c++) yd[c * 512 + t] = R[c];
            __syncthreads();
            cur ^= 1;
        }
    }
}

// ---------------- Stage M (MFMA): T[mode] = Xf[mode] @ conj(W[mode]) ---------
// Block = one mode (kxi, ky). GEMM M=32(b) N=64(o) K=64(i) complex:
//   Tr = Xr@Wr + Xi@Wi ; Ti = Xi@Wr - Xr@Wi (TiA - TiB at epilogue).
// X gathered from Xf[kxi][bi][ky] (16B grain); W gathered fp32 (L3-resident),
// both converted to split-bf16 oct-swizzled LDS planes in-block.
// 256 thr (4 waves); wave = (mt=wid&1, nt = wid>>1 and wid>>1 + 2).
// LDS 48 KiB: X planes 4x[32 b][64 i] @0; W planes 4x[64 o][64 i] @8192.
__global__ __launch_bounds__(256) void k_mix(const float2* __restrict__ xf,
                                             const float* __restrict__ w1r, const float* __restrict__ w1i,
                                             const float* __restrict__ w2r, const float* __restrict__ w2i,
                                             float2* __restrict__ tt) {
    __shared__ ushort lds[24576];  // 48 KiB
    const int kxi = blockIdx.x;    // 0..63
    const int ky  = blockIdx.y;    // 0..31
    const int t = threadIdx.x;
    const float* wr = (kxi < 32) ? w1r : w2r;
    const float* wi = (kxi < 32) ? w1i : w2i;
    const int kxim = kxi & 31;

    // Stage X[b=32][i=64]: A planes (Xr-h @0, Xr-l @2048, Xi-h @4096, Xi-l @6144).
    const float2* xp = xf + (size_t)kxi * 65536 + ky;
#pragma unroll
    for (int k = 0; k < 8; k++) {
        int idx = t + 256 * k;          // b*64 + i
        float2 v = xp[(size_t)idx * 32];
        int b = idx >> 6, i = idx & 63;
        int ad = b * 64 + ((((i >> 3) ^ (b & 7))) << 3) + (i & 7);
        ushort rh = f2bf(v.x), ih = f2bf(v.y);
        lds[ad] = rh;
        lds[2048 + ad] = f2bf(v.x - bf2f(rh));
        lds[4096 + ad] = ih;
        lds[6144 + ad] = f2bf(v.y - bf2f(ih));
    }
    // Stage W[i=64][o=64]: B planes (Wr-h @8192, Wr-l @12288, Wi-h @16384, Wi-l @20480).
    const size_t wbase = (size_t)kxim * 32 + ky;
#pragma unroll
    for (int k = 0; k < 16; k++) {
        int p = t + 256 * k;            // o*64 + i  (lanes vary i: LDS conflict-free)
        int o = p >> 6, i = p & 63;
        size_t g = ((size_t)i * 64 + o) * 1024 + wbase;
        float wrv = wr[g], wiv = wi[g];
        int ad = 8192 + o * 64 + ((((i >> 3) ^ (o & 7))) << 3) + (i & 7);
        ushort rh = f2bf(wrv), ih = f2bf(wiv);
        lds[ad] = rh;
        lds[4096 + ad] = f2bf(wrv - bf2f(rh));
        lds[8192 + ad] = ih;
        lds[12288 + ad] = f2bf(wiv - bf2f(ih));
    }
    __syncthreads();

    const int lane = t & 63, wid = t >> 6;
    const int ln = lane & 15, kq = lane >> 4;
    const int mt = wid & 1;
    f32x4 Tr[2] = {}, TiA[2] = {}, TiB[2] = {};
#pragma unroll
    for (int u = 0; u < 2; u++) {
        int nt = (wid >> 1) + u * 2;
        int o = nt * 16 + ln;
        int b = mt * 16 + ln;
#pragma unroll
        for (int kk = 0; kk < 2; kk++) {
            int aad = b * 64 + (((kk * 4 + kq) ^ (b & 7)) << 3);
            bf16x8 Xrh = *(const bf16x8*)&lds[aad];
            bf16x8 Xrl = *(const bf16x8*)&lds[2048 + aad];
            bf16x8 Xih = *(const bf16x8*)&lds[4096 + aad];
            bf16x8 Xil = *(const bf16x8*)&lds[6144 + aad];
            int bad = 8192 + o * 64 + (((kk * 4 + kq) ^ (o & 7)) << 3);
            bf16x8 Wrh = *(const bf16x8*)&lds[bad];
            bf16x8 Wrl = *(const bf16x8*)&lds[4096 + bad];
            bf16x8 Wih = *(const bf16x8*)&lds[8192 + bad];
            bf16x8 Wil = *(const bf16x8*)&lds[12288 + bad];
            Tr[u] = __builtin_amdgcn_mfma_f32_16x16x32_bf16(Xrh, Wrh, Tr[u], 0, 0, 0);
            Tr[u] = __builtin_amdgcn_mfma_f32_16x16x32_bf16(Xrh, Wrl, Tr[u], 0, 0, 0);
            Tr[u] = __builtin_amdgcn_mfma_f32_16x16x32_bf16(Xrl, Wrh, Tr[u], 0, 0, 0);
            Tr[u] = __builtin_amdgcn_mfma_f32_16x16x32_bf16(Xih, Wih, Tr[u], 0, 0, 0);
            Tr[u] = __builtin_amdgcn_mfma_f32_16x16x32_bf16(Xih, Wil, Tr[u], 0, 0, 0);
            Tr[u] = __builtin_amdgcn_mfma_f32_16x16x32_bf16(Xil, Wih, Tr[u], 0, 0, 0);
            TiA[u] = __builtin_amdgcn_mfma_f32_16x16x32_bf16(Xih, Wrh, TiA[u], 0, 0, 0);
            TiA[u] = __builtin_amdgcn_mfma_f32_16x16x32_bf16(Xih, Wrl, TiA[u], 0, 0, 0);
            TiA[u] = __builtin_amdgcn_mfma_f32_16x16x32_bf16(Xil, Wrh, TiA[u], 0, 0, 0);
            TiB[u] = __builtin_amdgcn_mfma_f32_16x16x32_bf16(Xrh, Wih, TiB[u], 0, 0, 0);
            TiB[u] = __builtin_amdgcn_mfma_f32_16x16x32_bf16(Xrh, Wil, TiB[u], 0, 0, 0);
            TiB[u] = __builtin_amdgcn_mfma_f32_16x16x32_bf16(Xrl, Wih, TiB[u], 0, 0, 0);
        }
    }
    // C layout: row = kq*4+r (b-local), col = ln (o-local). Coalesced 128B runs.
    float2* top = tt + ((size_t)kxi * 32 + ky) * 2048;
#pragma unroll
    for (int u = 0; u < 2; u++) {
        int nt = (wid >> 1) + u * 2;
        int o = nt * 16 + ln;
#pragma unroll
        for (int r = 0; r < 4; r++) {
            int b = mt * 16 + kq * 4 + r;
            top[b * 64 + o] = make_float2(Tr[u][r], TiA[u][r] - TiB[u][r]);
        }
    }
}

// ---------------- Stage INV (MFMA, fused I1+I2): T -> out --------------------
// T layout is now [mode=kxi*32+ky][bo]: stage is an L3-served gather.
#define G1_TILE(TT, ZRv, ZIv)                                                  \
    do {                                                                       \
        int mt1_ = (TT) & 3, nt1_ = (TT) >> 2;                                 \
        int arow_ = mt1_ * 16 + ln;                                            \
        int aad_ = arow_ * 40 + ((kq ^ (arow_ & 3)) << 3);                     \
        bf16x8 TRh_ = *(const bf16x8*)&lds[aad_];                              \
        bf16x8 TRl_ = *(const bf16x8*)&lds[2560 + aad_];                       \
        bf16x8 TIh_ = *(const bf16x8*)&lds[5120 + aad_];                       \
        bf16x8 TIl_ = *(const bf16x8*)&lds[7680 + aad_];                       \
        const ushort* bp_ = ew + (((nt1_ * 4 + kq) * 16 + ln) * 8);            \
        bf16x8 CWh_ = *(const bf16x8*)(bp_);                                   \
        bf16x8 CWl_ = *(const bf16x8*)(bp_ + 2560);                            \
        bf16x8 SWh_ = *(const bf16x8*)(bp_ + 5120);                            \
        bf16x8 SWl_ = *(const bf16x8*)(bp_ + 7680);                            \
        bf16x8 SNh_ = *(const bf16x8*)(bp_ + 10240);                           \
        bf16x8 SNl_ = *(const bf16x8*)(bp_ + 12800);                           \
        ZRv = __builtin_amdgcn_mfma_f32_16x16x32_bf16(TRh_, CWh_, ZRv, 0, 0, 0); \
        ZRv = __builtin_amdgcn_mfma_f32_16x16x32_bf16(TRh_, CWl_, ZRv, 0, 0, 0); \
        ZRv = __builtin_amdgcn_mfma_f32_16x16x32_bf16(TRl_, CWh_, ZRv, 0, 0, 0); \
        ZRv = __builtin_amdgcn_mfma_f32_16x16x32_bf16(TIh_, SNh_, ZRv, 0, 0, 0); \
        ZRv = __builtin_amdgcn_mfma_f32_16x16x32_bf16(TIh_, SNl_, ZRv, 0, 0, 0); \
        ZRv = __builtin_amdgcn_mfma_f32_16x16x32_bf16(TIl_, SNh_, ZRv, 0, 0, 0); \
        ZIv = __builtin_amdgcn_mfma_f32_16x16x32_bf16(TRh_, SWh_, ZIv, 0, 0, 0); \
        ZIv = __builtin_amdgcn_mfma_f32_16x16x32_bf16(TRh_, SWl_, ZIv, 0, 0, 0); \
        ZIv = __builtin_amdgcn_mfma_f32_16x16x32_bf16(TRl_, SWh_, ZIv, 0, 0, 0); \
        ZIv = __builtin_amdgcn_mfma_f32_16x16x32_bf16(TIh_, CWh_, ZIv, 0, 0, 0); \
        ZIv = __builtin_amdgcn_mfma_f32_16x16x32_bf16(TIh_, CWl_, ZIv, 0, 0, 0); \
        ZIv = __builtin_amdgcn_mfma_f32_16x16x32_bf16(TIl_, CWh_, ZIv, 0, 0, 0); \
    } while (0)

#define Z_STORE(TT, ZRv, ZIv)                                                  \
    do {                                                                       \
        int mt1_ = (TT) & 3, nt1_ = (TT) >> 2;                                 \
        int w_ = nt1_ * 16 + ln;                                               \
        int kxi_ = mt1_ * 16 + kq * 4;                                         \
        int octr_ = kxi_ >> 3, sub_ = kxi_ & 7;                                \
        int adr_ = w_ * 128 + ((octr_ ^ (w_ & 7)) << 3) + sub_;                \
        int adi_ = w_ * 128 + (((octr_ + 8) ^ (w_ & 7)) << 3) + sub_;          \
        ushort4 rh_, rl_, ih_, il_;                                            \
        float v0_ = ZRv[0], v1_ = ZRv[1], v2_ = ZRv[2], v3_ = ZRv[3];          \
        rh_.x = f2bf(v0_); rl_.x = f2bf(v0_ - bf2f(rh_.x));                    \
        rh_.y = f2bf(v1_); rl_.y = f2bf(v1_ - bf2f(rh_.y));                    \
        rh_.z = f2bf(v2_); rl_.z = f2bf(v2_ - bf2f(rh_.z));                    \
        rh_.w = f2bf(v3_); rl_.w = f2bf(v3_ - bf2f(rh_.w));                    \
        v0_ = -ZIv[0]; v1_ = -ZIv[1]; v2_ = -ZIv[2]; v3_ = -ZIv[3];            \
        ih_.x = f2bf(v0_); il_.x = f2bf(v0_ - bf2f(ih_.x));                    \
        ih_.y = f2bf(v1_); il_.y = f2bf(v1_ - bf2f(ih_.y));                    \
        ih_.z = f2bf(v2_); il_.z = f2bf(v2_ - bf2f(ih_.z));                    \
        ih_.w = f2bf(v3_); il_.w = f2bf(v3_ - bf2f(ih_.w));                    \
        *(ushort4*)&lds[adr_] = rh_;                                           \
        *(ushort4*)&lds[10240 + adr_] = rl_;                                   \
        *(ushort4*)&lds[adi_] = ih_;                                           \
        *(ushort4*)&lds[10240 + adi_] = il_;                                   \
    } while (0)

__global__ __launch_bounds__(512) void k_inv(const float2* __restrict__ tt,
                                             const ushort* __restrict__ ec,
                                             const ushort* __restrict__ ew,
                                             float* __restrict__ out) {
    __shared__ ushort lds[20480];  // 40 KiB
    const int bo = blockIdx.x, t = threadIdx.x;
    const int lane = t & 63, wid = t >> 6;
    const int ln = lane & 15, kq = lane >> 4;

    // EC A-fragments (GEMM2, const): issue early, used after GEMM1.
    bf16x8 ECh[4], ECl[4];
#pragma unroll
    for (int kk = 0; kk < 4; kk++) {
        const ushort* p = ec + ((((wid * 4 + kk) * 4 + kq) * 16 + ln) * 8);
        ECh[kk] = *(const bf16x8*)p;
        ECl[kk] = *(const bf16x8*)(p + 16384);
    }

    // Stage T (mode-major gather) -> split-bf16 A-planes [row 64][stride 40].
    const float2* tp = tt + bo;
    for (int i = t; i < 2048; i += 512) {
        float2 v = tp[(size_t)i * 2048];
        int row = i >> 5, ky = i & 31;
        int ad = row * 40 + ((((ky >> 3) ^ (row & 3))) << 3) + (ky & 7);
        ushort rh = f2bf(v.x), ih = f2bf(v.y);
        lds[ad] = rh;
        lds[2560 + ad] = f2bf(v.x - bf2f(rh));
        lds[5120 + ad] = ih;
        lds[7680 + ad] = f2bf(v.y - bf2f(ih));
    }
    __syncthreads();

    f32x4 ZR0 = {}, ZI0 = {}, ZR1 = {}, ZI1 = {}, ZR2 = {}, ZI2 = {};
    G1_TILE(wid, ZR0, ZI0);
    G1_TILE(wid + 8, ZR1, ZI1);
    if (wid < 4) G1_TILE(wid + 16, ZR2, ZI2);
    __syncthreads();

    Z_STORE(wid, ZR0, ZI0);
    Z_STORE(wid + 8, ZR1, ZI1);
    if (wid < 4) Z_STORE(wid + 16, ZR2, ZI2);
    __syncthreads();

    f32x4 acc[5] = {};
#pragma unroll
    for (int nt = 0; nt < 5; nt++) {
        int w = nt * 16 + ln;
#pragma unroll
        for (int kk = 0; kk < 4; kk++) {
            int oct = kk * 4 + kq;
            int ad = w * 128 + ((oct ^ (w & 7)) << 3);
            bf16x8 Bh = *(const bf16x8*)&lds[ad];
            bf16x8 Bl = *(const bf16x8*)&lds[10240 + ad];
            acc[nt] = __builtin_amdgcn_mfma_f32_16x16x32_bf16(ECh[kk], Bh, acc[nt], 0, 0, 0);
            acc[nt] = __builtin_amdgcn_mfma_f32_16x16x32_bf16(ECh[kk], Bl, acc[nt], 0, 0, 0);
            acc[nt] = __builtin_amdgcn_mfma_f32_16x16x32_bf16(ECl[kk], Bh, acc[nt], 0, 0, 0);
        }
    }
    float* op = out + (size_t)bo * 8320;
    const int h0 = wid * 16 + kq * 4;
#pragma unroll
    for (int nt = 0; nt < 5; nt++) {
        int w = nt * 16 + ln;
        if (w < 65) {
#pragma unroll
            for (int r = 0; r < 4; r++)
                op[(h0 + r) * 65 + w] = acc[nt][r];
        }
    }
}

extern "C" void kernel_launch(void* const* d_in, const int* in_sizes, int n_in,
                              void* d_out, int out_size, void* d_ws, size_t ws_size,
                              hipStream_t stream) {
    const float* x   = (const float*)d_in[0];
    const float* w1r = (const float*)d_in[1];
    const float* w1i = (const float*)d_in[2];
    const float* w2r = (const float*)d_in[3];
    const float* w2i = (const float*)d_in[4];
    float2* ws = (float2*)d_ws;

    // buf1 [0, 8388608) f2: Yimg (bf16 planes, 64 MB) then T (mode-major).
    // buf2 [8388608, +4194304) f2: Xf [kxi][bi][ky].
    // Constant images after Xf: e1 32 KiB, e2 64 KiB, ec 64 KiB, ew 30 KiB.
    ushort* yimg = (ushort*)ws;
    float2* ta   = ws;
    float2* xfa  = ws + 8388608;
    ushort* e1img = (ushort*)(ws + 12582912);
    ushort* e2img = (ushort*)(ws + 12587008);
    ushort* ecimg = (ushort*)(ws + 12595200);
    ushort* ewimg = (ushort*)(ws + 12603392);
    float* out = (float*)d_out;

    k_einit<<<160, 256, 0, stream>>>(e1img, e2img, ecimg, ewimg);
    k_f1<<<dim3(2048, 2), 256, 0, stream>>>(x, e1img, yimg);
    k_f2<<<256, 512, 0, stream>>>(yimg, e2img, xfa);
    k_mix<<<dim3(64, 32), 256, 0, stream>>>(xfa, w1r, w1i, w2r, w2i, ta);
    k_inv<<<2048, 512, 0, stream>>>(ta, ecimg, ewimg, out);
}